// Round 1
// baseline (160.056 us; speedup 1.0000x reference)
//
#include <hip/hip_runtime.h>
#include <stdint.h>

#define BATCH 256
#define NCAT  919
#define KDIM  400
#define NDIM  100
#define BK    32
#define NSTEP 13                    // ceil(400/32), last step has 16 valid k
#define NPAD  112                   // 7*16, padded N
#define LROW  40                    // padded LDS row length in bf16 elems (80B, 16B-aligned, bank-friendly)
#define ABUF  (BATCH * LROW)        // 10240 elems
#define WBUF  (NPAD * LROW)         // 4480 elems
#define BUFSZ (ABUF + WBUF)         // 14720 elems; total LDS = 2*BUFSZ*2B = 58880 B

typedef float  f32x4  __attribute__((ext_vector_type(4)));
typedef __bf16 bf16x8 __attribute__((ext_vector_type(8)));
typedef unsigned short u16;
typedef u16    u16x8  __attribute__((ext_vector_type(8)));

__device__ __forceinline__ u16 f2bf(float f) {
  union { float f; uint32_t u; } v; v.f = f;
  uint32_t r = v.u + 0x7fffu + ((v.u >> 16) & 1u);   // round-to-nearest-even
  return (u16)(r >> 16);
}

__global__ void __launch_bounds__(512, 4)
cat_dense(const float* __restrict__ in, const float* __restrict__ wt,
          const float* __restrict__ bias, float* __restrict__ out)
{
  __shared__ u16 lds[2 * BUFSZ];

  const int c    = blockIdx.x;
  const int tid  = threadIdx.x;
  const int lane = tid & 63;
  const int wave = tid >> 6;

  // --- staging geometry ---
  // A: 2 iters; iter i: row = (tid>>2) + i*128, k-chunk = (tid&3)*8 (8 floats = 2 float4)
  const int a_row = tid >> 2;
  const int a_kq  = (tid & 3) * 8;
  // W: threads 0..399; k-pair index kp=tid/25 (k = kb+2*kp, kb+2*kp+1), n-quad nq=(tid%25)*4
  const bool w_act = tid < 400;
  const int w_kp  = tid / 25;
  const int w_nq  = (tid - w_kp * 25) * 4;

  const float* gA = in + (size_t)c * KDIM;              // + row*(NCAT*KDIM) + k
  const float* gW = wt + (size_t)c * (KDIM * NDIM);     // + k*NDIM + n

  f32x4 areg[2][2];
  f32x4 wreg[2];

  auto load_step = [&](int t) {
    const int kb = t * BK;
    #pragma unroll
    for (int i = 0; i < 2; ++i) {
      const int row = a_row + i * 128;
      if (kb + a_kq < KDIM) {                           // 8-chunks align with K tail (400 = 12*32+16)
        const float* p = gA + (size_t)row * (NCAT * KDIM) + kb + a_kq;
        areg[i][0] = *(const f32x4*)p;
        areg[i][1] = *(const f32x4*)(p + 4);
      } else {
        areg[i][0] = {0.f,0.f,0.f,0.f};
        areg[i][1] = {0.f,0.f,0.f,0.f};
      }
    }
    const int k0 = kb + 2 * w_kp;
    if (w_act && k0 < KDIM) {                           // K even -> k0,k0+1 valid together
      const float* p = gW + (size_t)k0 * NDIM + w_nq;
      wreg[0] = *(const f32x4*)p;
      wreg[1] = *(const f32x4*)(p + NDIM);
    } else {
      wreg[0] = {0.f,0.f,0.f,0.f};
      wreg[1] = {0.f,0.f,0.f,0.f};
    }
  };

  // Always write (zeros for masked tail) so stale data from the previous use
  // of this buffer is overwritten.
  auto write_step = [&](int buf) {
    u16* L = &lds[buf * BUFSZ];
    #pragma unroll
    for (int i = 0; i < 2; ++i) {
      const int row = a_row + i * 128;
      u16x8 v;
      #pragma unroll
      for (int j = 0; j < 4; ++j) {
        v[j]     = f2bf(areg[i][0][j]);
        v[4 + j] = f2bf(areg[i][1][j]);
      }
      *(u16x8*)&L[row * LROW + a_kq] = v;               // 16B-aligned ds_write_b128
    }
    if (w_act) {
      u16* Lw = L + ABUF;
      #pragma unroll
      for (int j = 0; j < 4; ++j) {                     // transposed: Wt[n][k]
        uint32_t pk = (uint32_t)f2bf(wreg[0][j]) | ((uint32_t)f2bf(wreg[1][j]) << 16);
        *(uint32_t*)&Lw[(w_nq + j) * LROW + 2 * w_kp] = pk;
      }
    }
  };

  f32x4 acc[2][7];
  #pragma unroll
  for (int m = 0; m < 2; ++m)
    #pragma unroll
    for (int n = 0; n < 7; ++n)
      acc[m][n] = {0.f,0.f,0.f,0.f};

  const int rl = lane & 15;          // A-row / B-col / D-col within fragment
  const int kg = (lane >> 4) * 8;    // k offset within fragment

  auto compute = [&](int buf) {
    const u16* L  = &lds[buf * BUFSZ];
    const u16* Lw = L + ABUF;
    bf16x8 a0 = *(const bf16x8*)&L[(wave * 32 +      rl) * LROW + kg];
    bf16x8 a1 = *(const bf16x8*)&L[(wave * 32 + 16 + rl) * LROW + kg];
    #pragma unroll
    for (int n = 0; n < 7; ++n) {
      bf16x8 b = *(const bf16x8*)&Lw[(n * 16 + rl) * LROW + kg];
      acc[0][n] = __builtin_amdgcn_mfma_f32_16x16x32_bf16(a0, b, acc[0][n], 0, 0, 0);
      acc[1][n] = __builtin_amdgcn_mfma_f32_16x16x32_bf16(a1, b, acc[1][n], 0, 0, 0);
    }
  };

  // prologue: stage step 0 into buf 0
  load_step(0);
  write_step(0);
  __syncthreads();

  for (int t = 0; t < NSTEP; ++t) {
    const int buf = t & 1;
    if (t + 1 < NSTEP) load_step(t + 1);   // issue global loads early (hide HBM latency)
    compute(buf);
    if (t + 1 < NSTEP) {
      __syncthreads();                      // everyone done reading buf^1 (step t-1)
      write_step(buf ^ 1);                  // cvt + ds_write for step t+1
      __syncthreads();                      // writes visible
    }
  }

  // epilogue: C/D layout (16x16 family): col = lane&15, row = (lane>>4)*4 + reg
  const float* gB = bias + (size_t)c * NDIM;
  float* gO = out + (size_t)c * NDIM;
  #pragma unroll
  for (int n = 0; n < 7; ++n) {
    const int col = n * 16 + rl;
    if (col < NDIM) {
      const float bv = gB[col];
      #pragma unroll
      for (int m = 0; m < 2; ++m) {
        const int r0 = wave * 32 + m * 16 + (lane >> 4) * 4;
        #pragma unroll
        for (int j = 0; j < 4; ++j) {
          gO[(size_t)(r0 + j) * (NCAT * NDIM) + col] = acc[m][n][j] + bv;
        }
      }
    }
  }
}

extern "C" void kernel_launch(void* const* d_in, const int* in_sizes, int n_in,
                              void* d_out, int out_size, void* d_ws, size_t ws_size,
                              hipStream_t stream) {
  const float* in   = (const float*)d_in[0];
  const float* wt   = (const float*)d_in[1];
  const float* bias = (const float*)d_in[2];
  float* o          = (float*)d_out;
  cat_dense<<<dim3(NCAT), dim3(512), 0, stream>>>(in, wt, bias, o);
}